// Round 7
// baseline (230.971 us; speedup 1.0000x reference)
//
#include <hip/hip_runtime.h>
#include <cstdint>
#include <cstddef>

#define N_NODES 100000
#define N_EDGES 500000
#define IN_DIM  128
#define HID     512
#define N_CLS   40
#define N_SBLK  ((N_NODES + 255) / 256)   // 391 scan blocks
#define N_CNTB  ((N_EDGES + 255) / 256)   // 1954 count blocks
#define N_XBFB  12500                     // xbf blocks (3.2M float4)
#define N_G1B   12500                     // gather1 blocks (100000 / 8)
#define N_PREPB 352                       // W-prep blocks

typedef short bf16x8 __attribute__((ext_vector_type(8)));
typedef float f32x4 __attribute__((ext_vector_type(4)));

__device__ inline unsigned short f2bf(float f) {
  unsigned u = __float_as_uint(f);
  u = u + 0x7fffu + ((u >> 16) & 1u);          // RNE
  return (unsigned short)(u >> 16);
}
__device__ inline float blo(unsigned u) { return __uint_as_float(u << 16); }
__device__ inline float bhi(unsigned u) { return __uint_as_float(u & 0xffff0000u); }

// ---------------- CSR build ----------------
__global__ __launch_bounds__(256) void k_zero(int* __restrict__ cnt, unsigned* __restrict__ flags) {
  int i = blockIdx.x * 256 + threadIdx.x;
  if (i < N_NODES) cnt[i] = 0;
  if (i == 0) flags[0] = 0;                    // global segment allocator
}

// pure count; atomicAdd's return value IS the edge's rank within its dst segment.
__global__ __launch_bounds__(256) void k_count(const int* __restrict__ dst, int* __restrict__ cnt,
                                               int* __restrict__ rank) {
  int e = blockIdx.x * 256 + threadIdx.x;
  if (e < N_EDGES) rank[e] = atomicAdd(&cnt[dst[e]], 1);
}

// arrival-order scan: block base via ONE atomicAdd on a global allocator (order irrelevant —
// aggregation is an order-independent sum; consumers use offsets[d] + cnt[d] as segment end).
__global__ __launch_bounds__(256) void k_scan(const int* __restrict__ cnt, unsigned* __restrict__ flags,
                                              int* __restrict__ offsets, float* __restrict__ dinv) {
  __shared__ int s[256];
  __shared__ int base_sh;
  int b = blockIdx.x;
  int i = b * 256 + threadIdx.x;
  int v = (i < N_NODES) ? cnt[i] : 0;
  s[threadIdx.x] = v;
  __syncthreads();
  #pragma unroll
  for (int off = 1; off < 256; off <<= 1) {
    int t = (threadIdx.x >= off) ? s[threadIdx.x - off] : 0;
    __syncthreads();
    s[threadIdx.x] += t;
    __syncthreads();
  }
  int incl = s[threadIdx.x];
  if (threadIdx.x == 0)
    base_sh = (int)atomicAdd(&flags[0], (unsigned)s[255]);   // arrival-order base
  __syncthreads();
  if (i < N_NODES) {
    int excl = base_sh + incl - v;
    offsets[i] = excl;
    dinv[i]    = rsqrtf((float)(v + 1));       // +1 self-loop
  }
}

// atomic-free fill (pos = offsets[d] + rank[e]) fused with x->bf16 conversion
// (xbf output is consumed by the NEXT kernel — filler sits adjacent to its consumer).
__global__ __launch_bounds__(256) void k_fill_xbf(const int* __restrict__ src, const int* __restrict__ dst,
                                                  const int* __restrict__ rank, const int* __restrict__ offsets,
                                                  const float* __restrict__ dinv, int2* __restrict__ epair,
                                                  const float* __restrict__ x, uint2* __restrict__ xb2) {
  int b = blockIdx.x;
  if (b < N_CNTB) {
    int e = b * 256 + threadIdx.x;
    if (e >= N_EDGES) return;
    int s = src[e], d = dst[e];
    int pos = offsets[d] + rank[e];
    float nrm = dinv[s] * dinv[d];
    epair[pos] = make_int2(s, __float_as_int(nrm));
  } else {
    int t = (b - N_CNTB) * 256 + threadIdx.x;  // 3.2M exact
    float4 v = ((const float4*)x)[t];
    uint2 o;
    o.x = (unsigned)f2bf(v.x) | ((unsigned)f2bf(v.y) << 16);
    o.y = (unsigned)f2bf(v.z) | ((unsigned)f2bf(v.w) << 16);
    xb2[t] = o;
  }
}

// ---------------- layer-1 aggregation (gather, bf16): Z1 = Ahat @ X ----------------
// blocks [0,N_G1B): ONE node per 32-lane half (row = 32 x uint2 = 256B); 2 nodes/wave;
// 4-way unroll => 8 concurrent row chains per wave. Segment end = offsets[d] + cnt[d].
// blocks beyond: W1F/W2F prep (consumed by the NEXT kernel, k_fused_mfma).
__global__ __launch_bounds__(256) void k_gather1(const uint2* __restrict__ xb, const int2* __restrict__ ep,
                                                 const int* __restrict__ offsets, const int* __restrict__ cnt,
                                                 const float* __restrict__ dinv, uint2* __restrict__ z1,
                                                 const float* __restrict__ W1, const float* __restrict__ W2,
                                                 unsigned short* __restrict__ W1F, unsigned short* __restrict__ W2F) {
  int b = blockIdx.x;
  if (b >= N_G1B) {
    int t = (b - N_G1B) * 256 + threadIdx.x;   // 90112 exact
    if (t < 65536) {
      int j = t & 7, lane = (t >> 3) & 63, rest = t >> 9;   // rest = c*4+s
      int s2 = rest & 3, c = rest >> 2;
      int k = s2 * 32 + (lane >> 4) * 8 + j;
      int n = c * 16 + (lane & 15);
      W1F[t] = f2bf(W1[k * HID + n]);
    } else {
      int u = t - 65536;                        // 24576
      int j = u & 7, lane = (u >> 3) & 63, rest = u >> 9;   // rest = gk*3+ct
      int ct = rest % 3, gk = rest / 3;
      int k = gk * 32 + (lane >> 4) * 8 + j;
      int col = ct * 16 + (lane & 15);
      W2F[u] = (col < N_CLS) ? f2bf(W2[k * N_CLS + col]) : (unsigned short)0;
    }
    return;
  }
  int lane = threadIdx.x & 63, h = lane >> 5, l = lane & 31;
  int d = b * 8 + (threadIdx.x >> 6) * 2 + h;   // 12500 blocks x 8 = 100000 exact
  int start = offsets[d], end = start + cnt[d];
  float dd = dinv[d], sl = dd * dd;
  uint2 su = xb[(size_t)d * 32 + l];
  float a0 = sl * blo(su.x), a1 = sl * bhi(su.x), a2 = sl * blo(su.y), a3 = sl * bhi(su.y);
  float p0a = 0.f, p1a = 0.f, p2a = 0.f, p3a = 0.f;
  float q0a = 0.f, q1a = 0.f, q2a = 0.f, q3a = 0.f;
  float r0a = 0.f, r1a = 0.f, r2a = 0.f, r3a = 0.f;

  int i = start;
  for (; i + 3 < end; i += 4) {
    int2 e0 = ep[i], e1 = ep[i + 1], e2 = ep[i + 2], e3 = ep[i + 3];
    uint2 r0 = xb[(size_t)e0.x * 32 + l];
    uint2 r1 = xb[(size_t)e1.x * 32 + l];
    uint2 r2 = xb[(size_t)e2.x * 32 + l];
    uint2 r3 = xb[(size_t)e3.x * 32 + l];
    float n0 = __int_as_float(e0.y), n1 = __int_as_float(e1.y);
    float n2 = __int_as_float(e2.y), n3 = __int_as_float(e3.y);
    a0  += n0 * blo(r0.x); a1  += n0 * bhi(r0.x); a2  += n0 * blo(r0.y); a3  += n0 * bhi(r0.y);
    p0a += n1 * blo(r1.x); p1a += n1 * bhi(r1.x); p2a += n1 * blo(r1.y); p3a += n1 * bhi(r1.y);
    q0a += n2 * blo(r2.x); q1a += n2 * bhi(r2.x); q2a += n2 * blo(r2.y); q3a += n2 * bhi(r2.y);
    r0a += n3 * blo(r3.x); r1a += n3 * bhi(r3.x); r2a += n3 * blo(r3.y); r3a += n3 * bhi(r3.y);
  }
  for (; i < end; ++i) {
    int2 e0 = ep[i];
    uint2 r0 = xb[(size_t)e0.x * 32 + l];
    float n0 = __int_as_float(e0.y);
    a0 += n0 * blo(r0.x); a1 += n0 * bhi(r0.x); a2 += n0 * blo(r0.y); a3 += n0 * bhi(r0.y);
  }
  a0 += p0a + q0a + r0a;
  a1 += p1a + q1a + r1a;
  a2 += p2a + q2a + r2a;
  a3 += p3a + q3a + r3a;
  uint2 o;
  o.x = (unsigned)f2bf(a0) | ((unsigned)f2bf(a1) << 16);
  o.y = (unsigned)f2bf(a2) | ((unsigned)f2bf(a3) << 16);
  z1[(size_t)d * 32 + l] = o;
}

// ---------------- fused GEMM1+bias+relu+GEMM2 via bf16 MFMA ----------------
// 4 waves x 64 rows = 256 rows/block, 391 blocks. B-fragments staged in LDS once per
// block per g-group (11 KB: W1F chunk 8 KB + W2F chunk 3 KB, both contiguous in the
// prepacked layout), double-buffered, issue-early/write-late so HBM/L2 latency hides
// under compute. Cuts B L2-traffic 8x vs per-wave global reads (550 MB -> 69 MB).
// Epilogue: pair-swap (shfl_xor 1) + v_cvt_pk_bf16_f32 -> b32 LDS stores.
#define HS_STRIDE 56   // ushorts; 112B rows: 16B-aligned b128 reads, worst 2-way conflict = free
__global__ __launch_bounds__(256) void k_fused_mfma(const unsigned short* __restrict__ z1b,
                                                    const unsigned short* __restrict__ W1F,
                                                    const float* __restrict__ b1,
                                                    const unsigned short* __restrict__ W2F,
                                                    unsigned short* __restrict__ Pb) {
  __shared__ unsigned short Hs[4][64 * HS_STRIDE];   // 28672 B (per-wave H staging)
  __shared__ uint4 Bs[2][704];                        // 22528 B: [0,512)=W1F chunk, [512,704)=W2F chunk
  const int tid  = threadIdx.x;
  const int w    = tid >> 6, lane = tid & 63;
  const int c16  = lane & 15, quad = lane >> 4;
  const int odd  = c16 & 1;
  const int mbase = blockIdx.x * 256 + w * 64;        // 391 blocks x 256 >= 100000

  bf16x8 afrag[4][4];
  #pragma unroll
  for (int t = 0; t < 4; ++t) {
    int mrow = mbase + t * 16 + c16;
    int meff = (mrow < N_NODES) ? mrow : 0;
    const bf16x8* arow = (const bf16x8*)(z1b + (size_t)meff * IN_DIM + quad * 8);
    afrag[t][0] = arow[0];
    afrag[t][1] = arow[4];     // +32 ushorts
    afrag[t][2] = arow[8];
    afrag[t][3] = arow[12];
  }

  f32x4 pacc[4][3];
  #pragma unroll
  for (int t = 0; t < 4; ++t)
    #pragma unroll
    for (int ct = 0; ct < 3; ++ct) pacc[t][ct] = (f32x4){0.f, 0.f, 0.f, 0.f};

  const uint4* w1g = (const uint4*)W1F;   // 8192 uint4 total; chunk g = [g*512, g*512+512)
  const uint4* w2g = (const uint4*)W2F;   // 3072 uint4 total; chunk g = [g*192, g*192+192)
  unsigned short* hs = Hs[w];
  const int t2 = (tid < 192) ? tid : 191; // clamped W2F stage index

  // prologue: stage chunk 0 into Bs[0]
  Bs[0][tid]       = w1g[tid];
  Bs[0][tid + 256] = w1g[256 + tid];
  if (tid < 192) Bs[0][512 + tid] = w2g[t2];
  __syncthreads();

  for (int g = 0; g < 16; ++g) {               // 32 H-cols per group
    const int cur = g & 1;
    // issue next chunk's global loads EARLY (latency hides under this g's compute)
    uint4 s0, s1, s2;
    if (g < 15) {
      int gn = g + 1;
      s0 = w1g[gn * 512 + tid];
      s1 = w1g[gn * 512 + 256 + tid];
      s2 = w2g[gn * 192 + t2];
    }
    const bf16x8* b1f = (const bf16x8*)(&Bs[cur][0]);     // frag f at [f*64 + lane]
    const bf16x8* b2f = (const bf16x8*)(&Bs[cur][512]);

    #pragma unroll
    for (int nt = 0; nt < 2; ++nt) {
      int c = g * 2 + nt;                      // 16-col chunk
      bf16x8 bp0 = b1f[(nt * 4 + 0) * 64 + lane];
      bf16x8 bp1 = b1f[(nt * 4 + 1) * 64 + lane];
      bf16x8 bp2 = b1f[(nt * 4 + 2) * 64 + lane];
      bf16x8 bp3 = b1f[(nt * 4 + 3) * 64 + lane];
      f32x4 h[4];
      #pragma unroll
      for (int t = 0; t < 4; ++t) h[t] = (f32x4){0.f, 0.f, 0.f, 0.f};
      #pragma unroll
      for (int t = 0; t < 4; ++t) h[t] = __builtin_amdgcn_mfma_f32_16x16x32_bf16(afrag[t][0], bp0, h[t], 0, 0, 0);
      #pragma unroll
      for (int t = 0; t < 4; ++t) h[t] = __builtin_amdgcn_mfma_f32_16x16x32_bf16(afrag[t][1], bp1, h[t], 0, 0, 0);
      #pragma unroll
      for (int t = 0; t < 4; ++t) h[t] = __builtin_amdgcn_mfma_f32_16x16x32_bf16(afrag[t][2], bp2, h[t], 0, 0, 0);
      #pragma unroll
      for (int t = 0; t < 4; ++t) h[t] = __builtin_amdgcn_mfma_f32_16x16x32_bf16(afrag[t][3], bp3, h[t], 0, 0, 0);
      float bias = b1[c * 16 + c16];
      int colb = nt * 16 + (c16 & ~1);
      int rb0  = quad * 4 + (odd ? 2 : 0);
      #pragma unroll
      for (int t = 0; t < 4; ++t) {
        // C layout: lane (c16, quad) reg r -> (row = quad*4+r, col = c16)
        float v0 = fmaxf(h[t][0] + bias, 0.f);
        float v1 = fmaxf(h[t][1] + bias, 0.f);
        float v2 = fmaxf(h[t][2] + bias, 0.f);
        float v3 = fmaxf(h[t][3] + bias, 0.f);
        float o0 = __shfl_xor(v0, 1, 64);
        float o1 = __shfl_xor(v1, 1, 64);
        float o2 = __shfl_xor(v2, 1, 64);
        float o3 = __shfl_xor(v3, 1, 64);
        // even lane stores rows quad*4+{0,1}; odd lane rows quad*4+{2,3}; each b32 = (even col, odd col)
        float lo0 = odd ? o2 : v0, hi0 = odd ? v2 : o0;
        float lo1 = odd ? o3 : v1, hi1 = odd ? v3 : o1;
        unsigned p0, p1;
        asm("v_cvt_pk_bf16_f32 %0, %1, %2" : "=v"(p0) : "v"(lo0), "v"(hi0));   // RNE, == f2bf pair
        asm("v_cvt_pk_bf16_f32 %0, %1, %2" : "=v"(p1) : "v"(lo1), "v"(hi1));
        *(unsigned*)(hs + (t * 16 + rb0    ) * HS_STRIDE + colb) = p0;
        *(unsigned*)(hs + (t * 16 + rb0 + 1) * HS_STRIDE + colb) = p1;
      }
    }
    bf16x8 hf[4];
    #pragma unroll
    for (int t = 0; t < 4; ++t)
      hf[t] = *(const bf16x8*)(hs + (t * 16 + c16) * HS_STRIDE + quad * 8);
    #pragma unroll
    for (int ct = 0; ct < 3; ++ct) {
      bf16x8 bf = b2f[ct * 64 + lane];
      #pragma unroll
      for (int t = 0; t < 4; ++t)
        pacc[t][ct] = __builtin_amdgcn_mfma_f32_16x16x32_bf16(hf[t], bf, pacc[t][ct], 0, 0, 0);
    }
    // write-late: commit next chunk to the other buffer, then barrier
    if (g < 15) {
      const int nb = cur ^ 1;
      Bs[nb][tid]       = s0;
      Bs[nb][tid + 256] = s1;
      if (tid < 192) Bs[nb][512 + tid] = s2;
      __syncthreads();
    }
  }

  #pragma unroll
  for (int t = 0; t < 4; ++t) {
    int mrow0 = mbase + t * 16 + quad * 4;
    #pragma unroll
    for (int ct = 0; ct < 3; ++ct) {
      int col = ct * 16 + c16;
      if (col < N_CLS) {
        #pragma unroll
        for (int r = 0; r < 4; ++r) {
          int m = mrow0 + r;
          if (m < N_NODES) Pb[(size_t)m * N_CLS + col] = f2bf(pacc[t][ct][r]);
        }
      }
    }
  }
}

// ---------------- layer-2 aggregation (gather bf16, 40-dim) + bias + log_softmax ----------------
// ONE node per 16-lane quarter; 10 active lanes x uint2 (4 packed classes) = 80B row.
// 4 nodes/wave, 4-way unroll => 16 concurrent Pb-row chains per wave. float4 output.
// Segment end = offsets[d] + cnt[d].
__global__ __launch_bounds__(256) void k_gather2_lsm(const uint2* __restrict__ Pu2,
                                                     const int2* __restrict__ ep,
                                                     const int* __restrict__ offsets, const int* __restrict__ cnt,
                                                     const float* __restrict__ dinv, const float* __restrict__ b2,
                                                     float* __restrict__ out) {
  int lane = threadIdx.x & 63, q = lane >> 4, l = lane & 15;
  int d = blockIdx.x * 16 + (threadIdx.x >> 6) * 4 + q;   // 6250 blocks x 16 = 100000 exact
  bool act = l < 10;
  int lc = act ? l : 0;
  int start = offsets[d], end = start + cnt[d];
  float dd = dinv[d], sl = dd * dd;

  uint2 su = Pu2[(size_t)d * 10 + lc];
  float a0 = sl * blo(su.x), a1 = sl * bhi(su.x), a2 = sl * blo(su.y), a3 = sl * bhi(su.y);
  float p0a = 0.f, p1a = 0.f, p2a = 0.f, p3a = 0.f;
  float q0a = 0.f, q1a = 0.f, q2a = 0.f, q3a = 0.f;
  float r0a = 0.f, r1a = 0.f, r2a = 0.f, r3a = 0.f;

  int i = start;
  for (; i + 3 < end; i += 4) {
    int2 e0 = ep[i], e1 = ep[i + 1], e2 = ep[i + 2], e3 = ep[i + 3];
    uint2 u0 = Pu2[(size_t)e0.x * 10 + lc];
    uint2 u1 = Pu2[(size_t)e1.x * 10 + lc];
    uint2 u2 = Pu2[(size_t)e2.x * 10 + lc];
    uint2 u3 = Pu2[(size_t)e3.x * 10 + lc];
    float n0 = __int_as_float(e0.y), n1 = __int_as_float(e1.y);
    float n2 = __int_as_float(e2.y), n3 = __int_as_float(e3.y);
    a0  += n0 * blo(u0.x); a1  += n0 * bhi(u0.x); a2  += n0 * blo(u0.y); a3  += n0 * bhi(u0.y);
    p0a += n1 * blo(u1.x); p1a += n1 * bhi(u1.x); p2a += n1 * blo(u1.y); p3a += n1 * bhi(u1.y);
    q0a += n2 * blo(u2.x); q1a += n2 * bhi(u2.x); q2a += n2 * blo(u2.y); q3a += n2 * bhi(u2.y);
    r0a += n3 * blo(u3.x); r1a += n3 * bhi(u3.x); r2a += n3 * blo(u3.y); r3a += n3 * bhi(u3.y);
  }
  for (; i < end; ++i) {
    int2 e0 = ep[i];
    uint2 u0 = Pu2[(size_t)e0.x * 10 + lc];
    float n0 = __int_as_float(e0.y);
    a0 += n0 * blo(u0.x); a1 += n0 * bhi(u0.x); a2 += n0 * blo(u0.y); a3 += n0 * bhi(u0.y);
  }

  float v0, v1, v2, v3;
  if (act) {
    float4 bb = ((const float4*)b2)[l];
    v0 = a0 + p0a + q0a + r0a + bb.x;
    v1 = a1 + p1a + q1a + r1a + bb.y;
    v2 = a2 + p2a + q2a + r2a + bb.z;
    v3 = a3 + p3a + q3a + r3a + bb.w;
  } else {
    v0 = v1 = v2 = v3 = -1e30f;
  }
  // log-softmax over 40 classes held by 10 lanes of this quarter (shuffles stay in-quarter)
  float m = fmaxf(fmaxf(v0, v1), fmaxf(v2, v3));
  #pragma unroll
  for (int off = 8; off > 0; off >>= 1) m = fmaxf(m, __shfl_xor(m, off, 64));
  float e = act ? (expf(v0 - m) + expf(v1 - m) + expf(v2 - m) + expf(v3 - m)) : 0.f;
  float s = e;
  #pragma unroll
  for (int off = 8; off > 0; off >>= 1) s += __shfl_xor(s, off, 64);
  float lse = m + logf(s);
  if (act) {
    float4 o = make_float4(v0 - lse, v1 - lse, v2 - lse, v3 - lse);
    ((float4*)(out + (size_t)d * N_CLS))[l] = o;
  }
}

// ---------------- launcher ----------------
extern "C" void kernel_launch(void* const* d_in, const int* in_sizes, int n_in,
                              void* d_out, int out_size, void* d_ws, size_t ws_size,
                              hipStream_t stream) {
  const float* x  = (const float*)d_in[0];
  const int*   ei = (const int*)d_in[1];
  const int*  src = ei;                       // edge_index[0]
  const int*  dst = ei + N_EDGES;             // edge_index[1]
  const float* W1 = (const float*)d_in[2];
  const float* b1 = (const float*)d_in[3];
  const float* W2 = (const float*)d_in[4];
  const float* b2 = (const float*)d_in[5];
  float* out = (float*)d_out;

  // workspace layout (all 16B-aligned). Pb aliases xb2 (dead after k_gather1).
  float* dinv    = (float*)d_ws;                            // 131072 f
  int*   cnt     = (int*)(dinv + 131072);                   // 131072 i
  int*   offsets = cnt + 131072;                            // 131072 i
  unsigned* flags = (unsigned*)(offsets + 131072);          // 1024 u (only [0] used)
  int*   rank    = (int*)(flags + 1024);                    // 500000 i (pad to 524288)
  int2*  epair   = (int2*)(rank + 524288);                  // 500000 int2 (pad to 524288)
  uint2* xb2     = (uint2*)(epair + 524288);                // 3.2M uint2 (25.6 MB)
  unsigned short* Pb = (unsigned short*)xb2;                // alias: 4M us (8 MB) — xb dead by then
  unsigned short* z1b = (unsigned short*)(xb2 + 3200000);   // 12.8M us (25.6 MB)
  unsigned short* W1F = z1b + (size_t)N_NODES * IN_DIM;     // 65536 us
  unsigned short* W2F = W1F + HID * IN_DIM;                 // 24576 us

  k_zero    <<<N_SBLK, 256, 0, stream>>>(cnt, flags);
  k_count   <<<N_CNTB, 256, 0, stream>>>(dst, cnt, rank);
  k_scan    <<<N_SBLK, 256, 0, stream>>>(cnt, flags, offsets, dinv);
  k_fill_xbf<<<N_CNTB + N_XBFB, 256, 0, stream>>>(src, dst, rank, offsets, dinv, epair, x, xb2);
  k_gather1 <<<N_G1B + N_PREPB, 256, 0, stream>>>(xb2, epair, offsets, cnt, dinv, (uint2*)z1b,
                                                  W1, W2, W1F, W2F);
  k_fused_mfma<<<(N_NODES + 255) / 256, 256, 0, stream>>>(z1b, W1F, b1, W2F, Pb);
  k_gather2_lsm<<<N_NODES / 16, 256, 0, stream>>>((const uint2*)Pb, epair, offsets, cnt, dinv, b2, out);
}

// Round 8
// 221.106 us; speedup vs baseline: 1.0446x; 1.0446x over previous
//
#include <hip/hip_runtime.h>
#include <cstdint>
#include <cstddef>

#define N_NODES 100000
#define N_EDGES 500000
#define IN_DIM  128
#define HID     512
#define N_CLS   40
#define N_SBLK  ((N_NODES + 255) / 256)   // 391 scan blocks
#define N_CNTB  ((N_EDGES + 255) / 256)   // 1954 count blocks
#define N_XBFB  12500                     // xbf blocks (3.2M float4)
#define N_G1B   12500                     // gather1 blocks (100000 / 8)
#define N_PREPB 352                       // W-prep blocks

typedef short bf16x8 __attribute__((ext_vector_type(8)));
typedef float f32x4 __attribute__((ext_vector_type(4)));

__device__ inline unsigned short f2bf(float f) {
  unsigned u = __float_as_uint(f);
  u = u + 0x7fffu + ((u >> 16) & 1u);          // RNE
  return (unsigned short)(u >> 16);
}
__device__ inline float blo(unsigned u) { return __uint_as_float(u << 16); }
__device__ inline float bhi(unsigned u) { return __uint_as_float(u & 0xffff0000u); }

// ---------------- CSR build ----------------
__global__ __launch_bounds__(256) void k_zero(int* __restrict__ cnt, unsigned* __restrict__ flags) {
  int i = blockIdx.x * 256 + threadIdx.x;
  if (i < N_NODES) cnt[i] = 0;
  if (i == 0) flags[0] = 0;                    // global segment allocator
}

// pure count; atomicAdd's return value IS the edge's rank within its dst segment.
__global__ __launch_bounds__(256) void k_count(const int* __restrict__ dst, int* __restrict__ cnt,
                                               int* __restrict__ rank) {
  int e = blockIdx.x * 256 + threadIdx.x;
  if (e < N_EDGES) rank[e] = atomicAdd(&cnt[dst[e]], 1);
}

// arrival-order scan: block base via ONE atomicAdd on a global allocator (order irrelevant —
// aggregation is an order-independent sum; consumers use offsets[d] + cnt[d] as segment end).
__global__ __launch_bounds__(256) void k_scan(const int* __restrict__ cnt, unsigned* __restrict__ flags,
                                              int* __restrict__ offsets, float* __restrict__ dinv) {
  __shared__ int s[256];
  __shared__ int base_sh;
  int b = blockIdx.x;
  int i = b * 256 + threadIdx.x;
  int v = (i < N_NODES) ? cnt[i] : 0;
  s[threadIdx.x] = v;
  __syncthreads();
  #pragma unroll
  for (int off = 1; off < 256; off <<= 1) {
    int t = (threadIdx.x >= off) ? s[threadIdx.x - off] : 0;
    __syncthreads();
    s[threadIdx.x] += t;
    __syncthreads();
  }
  int incl = s[threadIdx.x];
  if (threadIdx.x == 0)
    base_sh = (int)atomicAdd(&flags[0], (unsigned)s[255]);   // arrival-order base
  __syncthreads();
  if (i < N_NODES) {
    int excl = base_sh + incl - v;
    offsets[i] = excl;
    dinv[i]    = rsqrtf((float)(v + 1));       // +1 self-loop
  }
}

// atomic-free fill (pos = offsets[d] + rank[e]) fused with x->bf16 conversion
// (xbf output is consumed by the NEXT kernel — filler sits adjacent to its consumer).
__global__ __launch_bounds__(256) void k_fill_xbf(const int* __restrict__ src, const int* __restrict__ dst,
                                                  const int* __restrict__ rank, const int* __restrict__ offsets,
                                                  const float* __restrict__ dinv, int2* __restrict__ epair,
                                                  const float* __restrict__ x, uint2* __restrict__ xb2) {
  int b = blockIdx.x;
  if (b < N_CNTB) {
    int e = b * 256 + threadIdx.x;
    if (e >= N_EDGES) return;
    int s = src[e], d = dst[e];
    int pos = offsets[d] + rank[e];
    float nrm = dinv[s] * dinv[d];
    epair[pos] = make_int2(s, __float_as_int(nrm));
  } else {
    int t = (b - N_CNTB) * 256 + threadIdx.x;  // 3.2M exact
    float4 v = ((const float4*)x)[t];
    uint2 o;
    o.x = (unsigned)f2bf(v.x) | ((unsigned)f2bf(v.y) << 16);
    o.y = (unsigned)f2bf(v.z) | ((unsigned)f2bf(v.w) << 16);
    xb2[t] = o;
  }
}

// ---------------- layer-1 aggregation (gather, bf16): Z1 = Ahat @ X ----------------
// blocks [0,N_G1B): ONE node per 32-lane half (row = 32 x uint2 = 256B); 2 nodes/wave;
// 4-way unroll => 8 concurrent row chains per wave. Segment end = offsets[d] + cnt[d].
// blocks beyond: W1F/W2F prep (consumed by the NEXT kernel, k_fused_mfma).
// W1F is packed for the SWAPPED-operand GEMM1 (W1F as the MFMA A operand): slot i=lane&15
// maps to H-column h = 32g + 8*(i>>2) + 4*nt + (i&3)  (c = 2g+nt), so the produced
// H^T tile registers line up exactly with GEMM2's K=32 A-fragment — no LDS transpose.
__global__ __launch_bounds__(256) void k_gather1(const uint2* __restrict__ xb, const int2* __restrict__ ep,
                                                 const int* __restrict__ offsets, const int* __restrict__ cnt,
                                                 const float* __restrict__ dinv, uint2* __restrict__ z1,
                                                 const float* __restrict__ W1, const float* __restrict__ W2,
                                                 unsigned short* __restrict__ W1F, unsigned short* __restrict__ W2F) {
  int b = blockIdx.x;
  if (b >= N_G1B) {
    int t = (b - N_G1B) * 256 + threadIdx.x;   // 90112 exact
    if (t < 65536) {
      int j = t & 7, lane = (t >> 3) & 63, rest = t >> 9;   // rest = c*4 + kfrag
      int kfrag = rest & 3, c = rest >> 2;                   // c = 2g + nt
      int k = kfrag * 32 + ((lane >> 4) & 3) * 8 + j;        // K index (z1 col)
      int i = lane & 15;                                     // A-row slot
      int h = (c >> 1) * 32 + (i >> 2) * 8 + (c & 1) * 4 + (i & 3);   // permuted H col
      W1F[t] = f2bf(W1[k * HID + h]);
    } else {
      int u = t - 65536;                        // 24576
      int j = u & 7, lane = (u >> 3) & 63, rest = u >> 9;   // rest = gk*3+ct
      int ct = rest % 3, gk = rest / 3;
      int k = gk * 32 + ((lane >> 4) & 3) * 8 + j;
      int col = ct * 16 + (lane & 15);
      W2F[u] = (col < N_CLS) ? f2bf(W2[k * N_CLS + col]) : (unsigned short)0;
    }
    return;
  }
  int lane = threadIdx.x & 63, h = lane >> 5, l = lane & 31;
  int d = b * 8 + (threadIdx.x >> 6) * 2 + h;   // 12500 blocks x 8 = 100000 exact
  int start = offsets[d], end = start + cnt[d];
  float dd = dinv[d], sl = dd * dd;
  uint2 su = xb[(size_t)d * 32 + l];
  float a0 = sl * blo(su.x), a1 = sl * bhi(su.x), a2 = sl * blo(su.y), a3 = sl * bhi(su.y);
  float p0a = 0.f, p1a = 0.f, p2a = 0.f, p3a = 0.f;
  float q0a = 0.f, q1a = 0.f, q2a = 0.f, q3a = 0.f;
  float r0a = 0.f, r1a = 0.f, r2a = 0.f, r3a = 0.f;

  int i = start;
  for (; i + 3 < end; i += 4) {
    int2 e0 = ep[i], e1 = ep[i + 1], e2 = ep[i + 2], e3 = ep[i + 3];
    uint2 r0 = xb[(size_t)e0.x * 32 + l];
    uint2 r1 = xb[(size_t)e1.x * 32 + l];
    uint2 r2 = xb[(size_t)e2.x * 32 + l];
    uint2 r3 = xb[(size_t)e3.x * 32 + l];
    float n0 = __int_as_float(e0.y), n1 = __int_as_float(e1.y);
    float n2 = __int_as_float(e2.y), n3 = __int_as_float(e3.y);
    a0  += n0 * blo(r0.x); a1  += n0 * bhi(r0.x); a2  += n0 * blo(r0.y); a3  += n0 * bhi(r0.y);
    p0a += n1 * blo(r1.x); p1a += n1 * bhi(r1.x); p2a += n1 * blo(r1.y); p3a += n1 * bhi(r1.y);
    q0a += n2 * blo(r2.x); q1a += n2 * bhi(r2.x); q2a += n2 * blo(r2.y); q3a += n2 * bhi(r2.y);
    r0a += n3 * blo(r3.x); r1a += n3 * bhi(r3.x); r2a += n3 * blo(r3.y); r3a += n3 * bhi(r3.y);
  }
  for (; i < end; ++i) {
    int2 e0 = ep[i];
    uint2 r0 = xb[(size_t)e0.x * 32 + l];
    float n0 = __int_as_float(e0.y);
    a0 += n0 * blo(r0.x); a1 += n0 * bhi(r0.x); a2 += n0 * blo(r0.y); a3 += n0 * bhi(r0.y);
  }
  a0 += p0a + q0a + r0a;
  a1 += p1a + q1a + r1a;
  a2 += p2a + q2a + r2a;
  a3 += p3a + q3a + r3a;
  uint2 o;
  o.x = (unsigned)f2bf(a0) | ((unsigned)f2bf(a1) << 16);
  o.y = (unsigned)f2bf(a2) | ((unsigned)f2bf(a3) << 16);
  z1[(size_t)d * 32 + l] = o;
}

// ---------------- fused GEMM1+bias+relu+GEMM2 via bf16 MFMA, swapped operands ----------------
// GEMM1 computes H^T tiles: D = mfma(W1F-frag (A), z1-frag (B)) -> lane c16 OWNS node c16's
// H values (rows = h). With the permuted W1F packing (see prep), this lane's 8 values across
// (nt, r) are exactly GEMM2's A-fragment k-slice (k = quad*8 + 4*nt + r). So bias+relu+cvt_pk
// feed GEMM2 directly from registers: NO LDS, NO barriers, NO shuffles, NO lgkm drains.
// 1 wave x 32 rows, 3125 blocks. All loads coalesced from L2/L3-resident W1F/W2F.
__global__ __launch_bounds__(64) void k_fused_mfma(const unsigned short* __restrict__ z1b,
                                                   const unsigned short* __restrict__ W1F,
                                                   const float* __restrict__ b1,
                                                   const unsigned short* __restrict__ W2F,
                                                   unsigned short* __restrict__ Pb) {
  const int lane = threadIdx.x;                   // 0..63 (one wave)
  const int c16  = lane & 15, quad = lane >> 4;
  const int mbase = blockIdx.x * 32;              // 3125 blocks x 32 = 100000 exact

  bf16x8 afrag[2][4];
  #pragma unroll
  for (int t = 0; t < 2; ++t) {
    int mrow = mbase + t * 16 + c16;              // always < N_NODES (exact grid)
    const bf16x8* arow = (const bf16x8*)(z1b + (size_t)mrow * IN_DIM + quad * 8);
    afrag[t][0] = arow[0];
    afrag[t][1] = arow[4];     // +32 ushorts
    afrag[t][2] = arow[8];
    afrag[t][3] = arow[12];
  }

  f32x4 pacc[2][3];
  #pragma unroll
  for (int t = 0; t < 2; ++t)
    #pragma unroll
    for (int ct = 0; ct < 3; ++ct) pacc[t][ct] = (f32x4){0.f, 0.f, 0.f, 0.f};

  const bf16x8* w1f = (const bf16x8*)W1F;
  const bf16x8* w2f = (const bf16x8*)W2F;
  const float4* b1v = (const float4*)b1;

  for (int g = 0; g < 16; ++g) {               // 32 H-cols per group
    bf16x8 wa[8];                              // f = nt*4 + kfrag
    #pragma unroll
    for (int f = 0; f < 8; ++f) wa[f] = w1f[(g * 8 + f) * 64 + lane];   // coalesced
    bf16x8 wb[3];
    #pragma unroll
    for (int ct = 0; ct < 3; ++ct) wb[ct] = w2f[(g * 3 + ct) * 64 + lane];
    float4 bb0 = b1v[g * 8 + quad * 2 + 0];    // bias for h = 32g + 8*quad + 0..3  (nt=0)
    float4 bb1 = b1v[g * 8 + quad * 2 + 1];    // bias for h = 32g + 8*quad + 4..7  (nt=1)

    #pragma unroll
    for (int t = 0; t < 2; ++t) {
      f32x4 h0 = (f32x4){0.f, 0.f, 0.f, 0.f};
      f32x4 h1 = (f32x4){0.f, 0.f, 0.f, 0.f};
      #pragma unroll
      for (int k = 0; k < 4; ++k)
        h0 = __builtin_amdgcn_mfma_f32_16x16x32_bf16(wa[k], afrag[t][k], h0, 0, 0, 0);
      #pragma unroll
      for (int k = 0; k < 4; ++k)
        h1 = __builtin_amdgcn_mfma_f32_16x16x32_bf16(wa[4 + k], afrag[t][k], h1, 0, 0, 0);
      // lane (c16=node, quad) holds H_pre[node][32g + 8*quad + 4*nt + r] in h{nt}[r]
      float e0 = fmaxf(h0[0] + bb0.x, 0.f), e1 = fmaxf(h0[1] + bb0.y, 0.f);
      float e2 = fmaxf(h0[2] + bb0.z, 0.f), e3 = fmaxf(h0[3] + bb0.w, 0.f);
      float f0 = fmaxf(h1[0] + bb1.x, 0.f), f1 = fmaxf(h1[1] + bb1.y, 0.f);
      float f2 = fmaxf(h1[2] + bb1.z, 0.f), f3 = fmaxf(h1[3] + bb1.w, 0.f);
      unsigned q0, q1, q2, q3;
      asm("v_cvt_pk_bf16_f32 %0, %1, %2" : "=v"(q0) : "v"(e0), "v"(e1));   // RNE, == f2bf
      asm("v_cvt_pk_bf16_f32 %0, %1, %2" : "=v"(q1) : "v"(e2), "v"(e3));
      asm("v_cvt_pk_bf16_f32 %0, %1, %2" : "=v"(q2) : "v"(f0), "v"(f1));
      asm("v_cvt_pk_bf16_f32 %0, %1, %2" : "=v"(q3) : "v"(f2), "v"(f3));
      union { unsigned u[4]; bf16x8 v; } pa;
      pa.u[0] = q0; pa.u[1] = q1; pa.u[2] = q2; pa.u[3] = q3;   // j = 4*nt + r  ✓ k=quad*8+j
      #pragma unroll
      for (int ct = 0; ct < 3; ++ct)
        pacc[t][ct] = __builtin_amdgcn_mfma_f32_16x16x32_bf16(pa.v, wb[ct], pacc[t][ct], 0, 0, 0);
    }
  }

  // P tile layout: col = ct*16 + c16, node = mbase + t*16 + quad*4 + r (same as before)
  #pragma unroll
  for (int t = 0; t < 2; ++t) {
    int mrow0 = mbase + t * 16 + quad * 4;
    #pragma unroll
    for (int ct = 0; ct < 3; ++ct) {
      int col = ct * 16 + c16;
      if (col < N_CLS) {
        #pragma unroll
        for (int r = 0; r < 4; ++r) {
          int m = mrow0 + r;                      // always < N_NODES (exact grid)
          Pb[(size_t)m * N_CLS + col] = f2bf(pacc[t][ct][r]);
        }
      }
    }
  }
}

// ---------------- layer-2 aggregation (gather bf16, 40-dim) + bias + log_softmax ----------------
// ONE node per 16-lane quarter; 10 active lanes x uint2 (4 packed classes) = 80B row.
// 4 nodes/wave, 4-way unroll => 16 concurrent Pb-row chains per wave. float4 output.
// Segment end = offsets[d] + cnt[d].
__global__ __launch_bounds__(256) void k_gather2_lsm(const uint2* __restrict__ Pu2,
                                                     const int2* __restrict__ ep,
                                                     const int* __restrict__ offsets, const int* __restrict__ cnt,
                                                     const float* __restrict__ dinv, const float* __restrict__ b2,
                                                     float* __restrict__ out) {
  int lane = threadIdx.x & 63, q = lane >> 4, l = lane & 15;
  int d = blockIdx.x * 16 + (threadIdx.x >> 6) * 4 + q;   // 6250 blocks x 16 = 100000 exact
  bool act = l < 10;
  int lc = act ? l : 0;
  int start = offsets[d], end = start + cnt[d];
  float dd = dinv[d], sl = dd * dd;

  uint2 su = Pu2[(size_t)d * 10 + lc];
  float a0 = sl * blo(su.x), a1 = sl * bhi(su.x), a2 = sl * blo(su.y), a3 = sl * bhi(su.y);
  float p0a = 0.f, p1a = 0.f, p2a = 0.f, p3a = 0.f;
  float q0a = 0.f, q1a = 0.f, q2a = 0.f, q3a = 0.f;
  float r0a = 0.f, r1a = 0.f, r2a = 0.f, r3a = 0.f;

  int i = start;
  for (; i + 3 < end; i += 4) {
    int2 e0 = ep[i], e1 = ep[i + 1], e2 = ep[i + 2], e3 = ep[i + 3];
    uint2 u0 = Pu2[(size_t)e0.x * 10 + lc];
    uint2 u1 = Pu2[(size_t)e1.x * 10 + lc];
    uint2 u2 = Pu2[(size_t)e2.x * 10 + lc];
    uint2 u3 = Pu2[(size_t)e3.x * 10 + lc];
    float n0 = __int_as_float(e0.y), n1 = __int_as_float(e1.y);
    float n2 = __int_as_float(e2.y), n3 = __int_as_float(e3.y);
    a0  += n0 * blo(u0.x); a1  += n0 * bhi(u0.x); a2  += n0 * blo(u0.y); a3  += n0 * bhi(u0.y);
    p0a += n1 * blo(u1.x); p1a += n1 * bhi(u1.x); p2a += n1 * blo(u1.y); p3a += n1 * bhi(u1.y);
    q0a += n2 * blo(u2.x); q1a += n2 * bhi(u2.x); q2a += n2 * blo(u2.y); q3a += n2 * bhi(u2.y);
    r0a += n3 * blo(u3.x); r1a += n3 * bhi(u3.x); r2a += n3 * blo(u3.y); r3a += n3 * bhi(u3.y);
  }
  for (; i < end; ++i) {
    int2 e0 = ep[i];
    uint2 u0 = Pu2[(size_t)e0.x * 10 + lc];
    float n0 = __int_as_float(e0.y);
    a0 += n0 * blo(u0.x); a1 += n0 * bhi(u0.x); a2 += n0 * blo(u0.y); a3 += n0 * bhi(u0.y);
  }

  float v0, v1, v2, v3;
  if (act) {
    float4 bb = ((const float4*)b2)[l];
    v0 = a0 + p0a + q0a + r0a + bb.x;
    v1 = a1 + p1a + q1a + r1a + bb.y;
    v2 = a2 + p2a + q2a + r2a + bb.z;
    v3 = a3 + p3a + q3a + r3a + bb.w;
  } else {
    v0 = v1 = v2 = v3 = -1e30f;
  }
  // log-softmax over 40 classes held by 10 lanes of this quarter (shuffles stay in-quarter)
  float m = fmaxf(fmaxf(v0, v1), fmaxf(v2, v3));
  #pragma unroll
  for (int off = 8; off > 0; off >>= 1) m = fmaxf(m, __shfl_xor(m, off, 64));
  float e = act ? (expf(v0 - m) + expf(v1 - m) + expf(v2 - m) + expf(v3 - m)) : 0.f;
  float s = e;
  #pragma unroll
  for (int off = 8; off > 0; off >>= 1) s += __shfl_xor(s, off, 64);
  float lse = m + logf(s);
  if (act) {
    float4 o = make_float4(v0 - lse, v1 - lse, v2 - lse, v3 - lse);
    ((float4*)(out + (size_t)d * N_CLS))[l] = o;
  }
}

// ---------------- launcher ----------------
extern "C" void kernel_launch(void* const* d_in, const int* in_sizes, int n_in,
                              void* d_out, int out_size, void* d_ws, size_t ws_size,
                              hipStream_t stream) {
  const float* x  = (const float*)d_in[0];
  const int*   ei = (const int*)d_in[1];
  const int*  src = ei;                       // edge_index[0]
  const int*  dst = ei + N_EDGES;             // edge_index[1]
  const float* W1 = (const float*)d_in[2];
  const float* b1 = (const float*)d_in[3];
  const float* W2 = (const float*)d_in[4];
  const float* b2 = (const float*)d_in[5];
  float* out = (float*)d_out;

  // workspace layout (all 16B-aligned). Pb aliases xb2 (dead after k_gather1).
  float* dinv    = (float*)d_ws;                            // 131072 f
  int*   cnt     = (int*)(dinv + 131072);                   // 131072 i
  int*   offsets = cnt + 131072;                            // 131072 i
  unsigned* flags = (unsigned*)(offsets + 131072);          // 1024 u (only [0] used)
  int*   rank    = (int*)(flags + 1024);                    // 500000 i (pad to 524288)
  int2*  epair   = (int2*)(rank + 524288);                  // 500000 int2 (pad to 524288)
  uint2* xb2     = (uint2*)(epair + 524288);                // 3.2M uint2 (25.6 MB)
  unsigned short* Pb = (unsigned short*)xb2;                // alias: 4M us (8 MB) — xb dead by then
  unsigned short* z1b = (unsigned short*)(xb2 + 3200000);   // 12.8M us (25.6 MB)
  unsigned short* W1F = z1b + (size_t)N_NODES * IN_DIM;     // 65536 us
  unsigned short* W2F = W1F + HID * IN_DIM;                 // 24576 us

  k_zero    <<<N_SBLK, 256, 0, stream>>>(cnt, flags);
  k_count   <<<N_CNTB, 256, 0, stream>>>(dst, cnt, rank);
  k_scan    <<<N_SBLK, 256, 0, stream>>>(cnt, flags, offsets, dinv);
  k_fill_xbf<<<N_CNTB + N_XBFB, 256, 0, stream>>>(src, dst, rank, offsets, dinv, epair, x, xb2);
  k_gather1 <<<N_G1B + N_PREPB, 256, 0, stream>>>(xb2, epair, offsets, cnt, dinv, (uint2*)z1b,
                                                  W1, W2, W1F, W2F);
  k_fused_mfma<<<N_NODES / 32, 64, 0, stream>>>(z1b, W1F, b1, W2F, Pb);
  k_gather2_lsm<<<N_NODES / 16, 256, 0, stream>>>((const uint2*)Pb, epair, offsets, cnt, dinv, b2, out);
}